// Round 3
// baseline (186.326 us; speedup 1.0000x reference)
//
#include <hip/hip_runtime.h>
#include <hip/hip_bf16.h>
#include <stdint.h>

#define NB 256
#define LQ 128
#define LC 512
#define DIM 384
#define TROWS 32
#define ROW_BYTES (DIM * 4)              // 1536
#define STAGE_BYTES (TROWS * ROW_BYTES)  // 49152
#define NSTAGE 12                        // 4 q-stages + 8 c-stages (half of LC)
#define CROWS_BLK 256                    // c rows per block
#define CBP 392                          // bf16 tile pitch in shorts

typedef __attribute__((ext_vector_type(8))) short short8;
typedef __attribute__((ext_vector_type(4))) float f4;
typedef __attribute__((ext_vector_type(2))) unsigned int u32x2;

__device__ __forceinline__ unsigned int pk2bf(float a, float b) {
  union { float f; uint32_t u; } x, y; x.f = a; y.f = b;
  uint32_t lo = (x.u + 0x7fffu + ((x.u >> 16) & 1u)) >> 16;
  uint32_t hi = (y.u + 0x7fffu + ((y.u >> 16) & 1u)) >> 16;
  return lo | (hi << 16);
}

__device__ __forceinline__ void gload16(const void* g, void* l) {
  __builtin_amdgcn_global_load_lds(
      (const __attribute__((address_space(1))) void*)g,
      (__attribute__((address_space(3))) void*)l, 16, 0, 0);
}

__device__ __forceinline__ void bar_lgkm() {
  asm volatile("s_waitcnt lgkmcnt(0)" ::: "memory");
  __builtin_amdgcn_s_barrier();
  __builtin_amdgcn_sched_barrier(0);
}

// Grid 512: block = (batch b = bid>>1, c-half = bid&1). 8 waves.
// Single 48KB f32 DMA buffer (each wave owns its 4-row region for both DMA
// and reads -> no cross-wave hazard, no double buffer), single bf16 tile.
// 12 stages: 4 q (A-fragment grab) + 8 c (MFMA + masked max-fold).
// Partial results (row-max per half, pooled partials) -> d_ws; merged by K2.
__global__ __launch_bounds__(512, 4)
void fused_pool_late(const float* __restrict__ qtok, const float* __restrict__ ctok,
                     const int* __restrict__ qm, const int* __restrict__ cm,
                     float* __restrict__ ws_rm, float* __restrict__ ws_pq,
                     float* __restrict__ ws_pc, float* __restrict__ ws_nq,
                     float* __restrict__ ws_nc) {
  __shared__ float fbuf[TROWS * DIM];         // 49152 B (single buffer)
  __shared__ unsigned short s_cb[TROWS][CBP]; // 25088 B
  __shared__ float s_qinv[LQ];
  __shared__ float s_cinv[TROWS];
  __shared__ int s_qm[LQ];
  __shared__ int s_cm[CROWS_BLK];
  __shared__ float s_cnt[16];

  const int bid = blockIdx.x;
  const int b = bid >> 1, half = bid & 1;
  const int tid = threadIdx.x;
  const int wave = tid >> 6, lane = tid & 63;
  const int rA = lane & 15, hi = lane >> 4;

  const char* qb = (const char*)(qtok + (size_t)b * LQ * DIM);
  const char* cb = (const char*)(ctok + (size_t)b * LC * DIM) + (size_t)half * CROWS_BLK * ROW_BYTES;

  if (tid < LQ) s_qm[tid] = qm[b * LQ + tid];
  if (tid < CROWS_BLK) s_cm[tid] = cm[b * LC + half * CROWS_BLK + tid];
  __syncthreads();

  // swizzled per-lane DMA source offsets (proven in round 2):
  // LDS 16B-chunk n holds global chunk (n%96) ^ (row&7), row = n/96.
  int goff[6];
#pragma unroll
  for (int j = 0; j < 6; ++j) {
    unsigned n = (unsigned)wave * 384u + (unsigned)j * 64u + (unsigned)lane;
    unsigned row = n / 96u, cc = n % 96u;
    goff[j] = (int)(row * ROW_BYTES + ((cc ^ (row & 7u)) << 4));
  }
  char* ldst = (char*)&fbuf[0] + wave * 6144;  // wave-owned region

  // prologue: stage 0 (q rows 0..31)
#pragma unroll
  for (int j = 0; j < 6; ++j) gload16(qb + goff[j], ldst + j * 1024);

  f4 pqa = {0.f,0.f,0.f,0.f}, pqb = {0.f,0.f,0.f,0.f};
  f4 pca = {0.f,0.f,0.f,0.f}, pcb = {0.f,0.f,0.f,0.f};
  float cq = 0.f, ccnt = 0.f;
  float rm[4] = {-1e9f, -1e9f, -1e9f, -1e9f};
  short8 A[12] = {};

  for (int t = 0; t < NSTAGE; ++t) {
    asm volatile("s_waitcnt vmcnt(0)" ::: "memory");  // own DMA for stage t landed
    __builtin_amdgcn_sched_barrier(0);

    // ---- A-phase reads: own 4 rows of fbuf
    const char* fb = (const char*)&fbuf[0];
    const bool isq = (t < 4);
    f4 va[4], vb[4];
#pragma unroll
    for (int r0 = 0; r0 < 4; ++r0) {
      const int lrow = wave * 4 + r0;
      const int k7 = lrow & 7;
      va[r0] = *(const f4*)(fb + lrow * ROW_BYTES + ((lane ^ k7) << 4));
      vb[r0] = (f4){0.f,0.f,0.f,0.f};
      if (lane < 32) vb[r0] = *(const f4*)(fb + lrow * ROW_BYTES + (((64 + lane) ^ k7) << 4));
    }
    asm volatile("s_waitcnt lgkmcnt(0)" ::: "memory");  // values in regs
    __builtin_amdgcn_sched_barrier(0);

    // ---- issue next stage's DMA into own (now-free) region
    if (t + 1 < NSTAGE) {
      const char* base = (t + 1 < 4) ? (qb + (size_t)(t + 1) * STAGE_BYTES)
                                     : (cb + (size_t)(t + 1 - 4) * STAGE_BYTES);
#pragma unroll
      for (int j = 0; j < 6; ++j) gload16(base + goff[j], ldst + j * 1024);
    }

    // ---- A-phase compute
#pragma unroll
    for (int r0 = 0; r0 < 4; ++r0) {
      const int lrow = wave * 4 + r0;
      const f4 a = va[r0], bb = vb[r0];
      float ss = a.x*a.x + a.y*a.y + a.z*a.z + a.w*a.w
               + bb.x*bb.x + bb.y*bb.y + bb.z*bb.z + bb.w*bb.w;
#pragma unroll
      for (int o = 32; o; o >>= 1) ss += __shfl_xor(ss, o);
      const float inv = 1.0f / fmaxf(sqrtf(ss), 1e-12f);
      const int mk = isq ? s_qm[t * 32 + lrow] : s_cm[(t - 4) * 32 + lrow];
      const float fm = (float)mk;
      if (isq) {
        pqa += a * fm; pqb += bb * fm; cq += fm;
        if (lane == 0) s_qinv[t * 32 + lrow] = inv;
      } else {
        pca += a * fm; pcb += bb * fm; ccnt += fm;
        if (lane == 0) s_cinv[lrow] = inv;
      }
      u32x2 w0; w0[0] = pk2bf(a.x, a.y); w0[1] = pk2bf(a.z, a.w);
      *(u32x2*)&s_cb[lrow][4 * lane] = w0;
      if (lane < 32) {
        u32x2 w1; w1[0] = pk2bf(bb.x, bb.y); w1[1] = pk2bf(bb.z, bb.w);
        *(u32x2*)&s_cb[lrow][256 + 4 * lane] = w1;
      }
    }
    bar_lgkm();  // s_cb / inv visible; DMA stays in flight

    // ---- C-phase
    if (isq) {
      if ((wave >> 1) == t) {  // waves 2t,2t+1 own q rows [32t,32t+32)
        const int lbase = (wave & 1) * 16 + rA;
#pragma unroll
        for (int kk = 0; kk < 12; ++kk)
          A[kk] = *(const short8*)&s_cb[lbase][kk * 32 + hi * 8];
        asm volatile("s_waitcnt lgkmcnt(0)" ::: "memory");
        __builtin_amdgcn_sched_barrier(0);
      }
    } else {
      f4 acc0 = {0.f,0.f,0.f,0.f}, acc1 = {0.f,0.f,0.f,0.f};
#pragma unroll
      for (int kk = 0; kk < 12; ++kk) {
        const short8 b0 = *(const short8*)&s_cb[rA][kk * 32 + hi * 8];
        const short8 b1 = *(const short8*)&s_cb[rA + 16][kk * 32 + hi * 8];
        acc0 = __builtin_amdgcn_mfma_f32_16x16x32_bf16(A[kk], b0, acc0, 0, 0, 0);
        acc1 = __builtin_amdgcn_mfma_f32_16x16x32_bf16(A[kk], b1, acc1, 0, 0, 0);
      }
      const int tb = (t - 4) * 32;
      const bool v0 = s_cm[tb + rA] != 0;
      const bool v1 = s_cm[tb + rA + 16] != 0;
      const float ci0 = s_cinv[rA], ci1 = s_cinv[rA + 16];
#pragma unroll
      for (int r = 0; r < 4; ++r) {
        const float qi = s_qinv[wave * 16 + hi * 4 + r];
        const float a0 = v0 ? acc0[r] * (qi * ci0) : -1e9f;
        const float a1 = v1 ? acc1[r] * (qi * ci1) : -1e9f;
        rm[r] = fmaxf(rm[r], fmaxf(a0, a1));
      }
    }
    __builtin_amdgcn_s_barrier();  // s_cb free for next stage's writes
    __builtin_amdgcn_sched_barrier(0);
  }

  // ---- write per-half row-maxes (reduce across the 16 col-lanes)
#pragma unroll
  for (int r = 0; r < 4; ++r) {
#pragma unroll
    for (int o = 1; o < 16; o <<= 1) rm[r] = fmaxf(rm[r], __shfl_xor(rm[r], o));
  }
  if (rA == 0) {
    const int rowb = wave * 16 + hi * 4;
#pragma unroll
    for (int r = 0; r < 4; ++r)
      ws_rm[(size_t)bid * LQ + rowb + r] = rm[r];
  }

  // ---- pooled partials: reduce 8 waves via fbuf (free now; after barrier)
  float* red = (float*)&fbuf[0];
  *(f4*)&red[wave * DIM + 4 * lane] = pqa;
  if (lane < 32) *(f4*)&red[wave * DIM + 256 + 4 * lane] = pqb;
  *(f4*)&red[(8 + wave) * DIM + 4 * lane] = pca;
  if (lane < 32) *(f4*)&red[(8 + wave) * DIM + 256 + 4 * lane] = pcb;
  if (lane == 0) { s_cnt[wave] = cq; s_cnt[8 + wave] = ccnt; }
  __syncthreads();

  if (tid < DIM) {
    float sq = 0.f, sc = 0.f, nq = 0.f, nc = 0.f;
#pragma unroll
    for (int w = 0; w < 8; ++w) {
      sq += red[w * DIM + tid];
      sc += red[(8 + w) * DIM + tid];
      nq += s_cnt[w];
      nc += s_cnt[8 + w];
    }
    if (half == 0) ws_pq[(size_t)b * DIM + tid] = sq;
    ws_pc[(size_t)bid * DIM + tid] = sc;
    if (tid == 0) {
      if (half == 0) ws_nq[b] = nq;
      ws_nc[bid] = nc;
    }
  }
}

// K2: merge halves -> late[b]; pooled -> 2-row MLP -> emb rows b (q), NB+b (c).
__global__ __launch_bounds__(DIM)
void epilogue_mlp(const float* __restrict__ ws_rm, const float* __restrict__ ws_pq,
                  const float* __restrict__ ws_pc, const float* __restrict__ ws_nq,
                  const float* __restrict__ ws_nc, const int* __restrict__ qm,
                  const float* __restrict__ W1, const float* __restrict__ b1,
                  const float* __restrict__ W2, const float* __restrict__ b2,
                  float* __restrict__ late, float* __restrict__ emb) {
  __shared__ float s_q[DIM], s_c[DIM], s_hq[DIM], s_hc[DIM];
  __shared__ float s_red[2][6], s_l[2];
  const int b = blockIdx.x;
  const int d = threadIdx.x;

  if (d < LQ) {
    const float m = fmaxf(ws_rm[(size_t)(2 * b) * LQ + d],
                          ws_rm[(size_t)(2 * b + 1) * LQ + d]);
    float ps = qm[b * LQ + d] ? m : 0.f;
#pragma unroll
    for (int o = 32; o; o >>= 1) ps += __shfl_xor(ps, o);
    if ((d & 63) == 0) s_l[d >> 6] = ps;
  }
  const float nq = fmaxf(ws_nq[b], 1e-9f);
  const float nc = fmaxf(ws_nc[2 * b] + ws_nc[2 * b + 1], 1e-9f);
  s_q[d] = ws_pq[(size_t)b * DIM + d] / nq;
  s_c[d] = (ws_pc[(size_t)(2 * b) * DIM + d] + ws_pc[(size_t)(2 * b + 1) * DIM + d]) / nc;
  __syncthreads();

  float aq = b1[d], ac = b1[d];
#pragma unroll 8
  for (int k = 0; k < DIM; ++k) {
    const float w = W1[k * DIM + d];
    aq = fmaf(s_q[k], w, aq);
    ac = fmaf(s_c[k], w, ac);
  }
  s_hq[d] = fmaxf(aq, 0.f);
  s_hc[d] = fmaxf(ac, 0.f);
  __syncthreads();
  float pq = b2[d], pc = b2[d];
#pragma unroll 8
  for (int k = 0; k < DIM; ++k) {
    const float w = W2[k * DIM + d];
    pq = fmaf(s_hq[k], w, pq);
    pc = fmaf(s_hc[k], w, pc);
  }
  float sq = pq * pq, sc = pc * pc;
#pragma unroll
  for (int o = 32; o; o >>= 1) { sq += __shfl_xor(sq, o); sc += __shfl_xor(sc, o); }
  if ((d & 63) == 0) { s_red[0][d >> 6] = sq; s_red[1][d >> 6] = sc; }
  __syncthreads();
  float tq = 0.f, tc = 0.f;
#pragma unroll
  for (int w = 0; w < 6; ++w) { tq += s_red[0][w]; tc += s_red[1][w]; }
  emb[(size_t)b * DIM + d] = pq * (1.0f / fmaxf(sqrtf(tq), 1e-12f));
  emb[(size_t)(NB + b) * DIM + d] = pc * (1.0f / fmaxf(sqrtf(tc), 1e-12f));
  if (d == 0) late[b] = s_l[0] + s_l[1];
}

// K3: out0[i][j] = dot(q_emb[i], c_emb[j]) / 0.07  (round-1 proven shape)
__global__ __launch_bounds__(NB)
void contrast_kernel(const float* __restrict__ emb, float* __restrict__ out0) {
  __shared__ float s_q[DIM];
  const int i = blockIdx.x;
  for (int k = threadIdx.x; k < DIM; k += NB) s_q[k] = emb[(size_t)i * DIM + k];
  __syncthreads();
  const float* ce = emb + (size_t)(NB + threadIdx.x) * DIM;
  float acc = 0.f;
#pragma unroll 8
  for (int k = 0; k < DIM; ++k) acc = fmaf(s_q[k], ce[k], acc);
  out0[(size_t)i * NB + threadIdx.x] = acc / 0.07f;
}

extern "C" void kernel_launch(void* const* d_in, const int* in_sizes, int n_in,
                              void* d_out, int out_size, void* d_ws, size_t ws_size,
                              hipStream_t stream) {
  const float* qtok = (const float*)d_in[0];
  const float* ctok = (const float*)d_in[1];
  const int*   qmm  = (const int*)d_in[2];
  const int*   cmm  = (const int*)d_in[3];
  const float* W1   = (const float*)d_in[4];
  const float* b1   = (const float*)d_in[5];
  const float* W2   = (const float*)d_in[6];
  const float* b2   = (const float*)d_in[7];

  float* out0 = (float*)d_out;        // [NB*NB]
  float* late = out0 + NB * NB;       // [NB]

  float* ws_rm = (float*)d_ws;              // [2*NB][LQ]
  float* ws_pq = ws_rm + 2 * NB * LQ;       // [NB][DIM]
  float* ws_pc = ws_pq + NB * DIM;          // [2*NB][DIM]
  float* ws_nq = ws_pc + 2 * NB * DIM;      // [NB]
  float* ws_nc = ws_nq + NB;                // [2*NB]
  float* emb   = ws_nc + 2 * NB;            // [2*NB][DIM]

  hipLaunchKernelGGL(fused_pool_late, dim3(2 * NB), dim3(512), 0, stream,
                     qtok, ctok, qmm, cmm, ws_rm, ws_pq, ws_pc, ws_nq, ws_nc);
  hipLaunchKernelGGL(epilogue_mlp, dim3(NB), dim3(DIM), 0, stream,
                     ws_rm, ws_pq, ws_pc, ws_nq, ws_nc, qmm, W1, b1, W2, b2,
                     late, emb);
  hipLaunchKernelGGL(contrast_kernel, dim3(NB), dim3(NB), 0, stream, emb, out0);
}

// Round 4
// 157.421 us; speedup vs baseline: 1.1836x; 1.1836x over previous
//
#include <hip/hip_runtime.h>
#include <hip/hip_bf16.h>
#include <stdint.h>

#define NB 256
#define LQ 128
#define LC 512
#define DIM 384
#define TR 32                    // rows per stage
#define STAGE_BYTES (TR * DIM * 4)  // 49152
#define NQS 4                    // q stages
#define NCS 16                   // c stages
#define CBP 392                  // bf16 tile pitch in shorts

typedef __attribute__((ext_vector_type(8))) short short8;
typedef __attribute__((ext_vector_type(4))) float f4;
typedef __attribute__((ext_vector_type(2))) unsigned int u32x2;

__device__ __forceinline__ unsigned int pk2bf(float a, float b) {
  union { float f; uint32_t u; } x, y; x.f = a; y.f = b;
  uint32_t lo = (x.u + 0x7fffu + ((x.u >> 16) & 1u)) >> 16;
  uint32_t hi = (y.u + 0x7fffu + ((y.u >> 16) & 1u)) >> 16;
  return lo | (hi << 16);
}

__device__ __forceinline__ void bar_lgkm() {
  asm volatile("s_waitcnt lgkmcnt(0)" ::: "memory");
  __builtin_amdgcn_s_barrier();
  __builtin_amdgcn_sched_barrier(0);
}

// Issue next stage's global loads into a register bank (8 loads/lane issued,
// consumed one full stage later -> loads stay in flight across the whole
// stage incl. barriers; barriers never drain vmcnt).
__device__ __forceinline__ void prefetch_stage(const char* base, int wave, int lane,
                                               f4 (&va)[4], f4 (&vb)[4]) {
  if (!base) return;
#pragma unroll
  for (int r = 0; r < 4; ++r) {
    const char* p = base + (size_t)(wave * 4 + r) * 1536;
    va[r] = *(const f4*)(p + lane * 16);
    vb[r] = *(const f4*)(p + 1024 + (lane & 31) * 16);  // lanes>=32: dup, unused
  }
}

// Consume a register bank: row sumsq -> inv norm, masked pooled partials,
// bf16 convert + ds_write into s_cb (single buffer; barriers separate uses).
template <bool ISQ>
__device__ __forceinline__ void stage_compute(
    int t, f4 (&va)[4], f4 (&vb)[4], int wave, int lane,
    const int* s_qm, const int* s_cm, unsigned short (*s_cb)[CBP],
    float* s_qinv, float* s_cinv,
    f4& p0, f4& p1, float& cnt) {
#pragma unroll
  for (int r = 0; r < 4; ++r) {
    const int lrow = wave * 4 + r;
    const f4 a = va[r], bb = vb[r];
    float sb = (lane < 32) ? (bb.x*bb.x + bb.y*bb.y + bb.z*bb.z + bb.w*bb.w) : 0.f;
    float ss = a.x*a.x + a.y*a.y + a.z*a.z + a.w*a.w + sb;
#pragma unroll
    for (int o = 32; o; o >>= 1) ss += __shfl_xor(ss, o);
    const float inv = 1.0f / fmaxf(sqrtf(ss), 1e-12f);
    const int mk = ISQ ? s_qm[t * TR + lrow] : s_cm[t * TR + lrow];
    const float fm = (float)mk;
    p0 += a * fm;
    if (lane < 32) p1 += bb * fm;
    cnt += fm;
    if (lane == 0) { if (ISQ) s_qinv[t * TR + lrow] = inv; else s_cinv[lrow] = inv; }
    u32x2 w0; w0[0] = pk2bf(a.x, a.y); w0[1] = pk2bf(a.z, a.w);
    *(u32x2*)&s_cb[lrow][4 * lane] = w0;
    if (lane < 32) {
      u32x2 w1; w1[0] = pk2bf(bb.x, bb.y); w1[1] = pk2bf(bb.z, bb.w);
      *(u32x2*)&s_cb[lrow][256 + 4 * lane] = w1;
    }
  }
}

// One block per batch (grid 256). 8 waves. Register-staged pipeline:
// 4 q stages (A-fragment capture) + 16 c stages (MFMA + masked max-fold).
__global__ __launch_bounds__(512, 2)
void fused_pool_late(const float* __restrict__ qtok, const float* __restrict__ ctok,
                     const int* __restrict__ qm, const int* __restrict__ cm,
                     float* __restrict__ pooled, float* __restrict__ late) {
  __shared__ unsigned short s_cb[TR][CBP];  // 25088 B (also reused as f32 scratch)
  __shared__ float s_qinv[LQ];
  __shared__ float s_cinv[TR];
  __shared__ int s_qm[LQ];
  __shared__ int s_cm[LC];
  __shared__ float s_cnt[16];
  __shared__ float s_wsum[8];

  const int b = blockIdx.x;
  const int tid = threadIdx.x;
  const int wave = tid >> 6, lane = tid & 63;
  const int rA = lane & 15, hi = lane >> 4;

  const char* qbase = (const char*)(qtok + (size_t)b * LQ * DIM);
  const char* cbase = (const char*)(ctok + (size_t)b * LC * DIM);

  if (tid < LQ) s_qm[tid] = qm[b * LQ + tid];
  s_cm[tid] = cm[b * LC + tid];
  __syncthreads();

  f4 va0[4], vb0[4], va1[4], vb1[4];
  f4 pq0 = {0,0,0,0}, pq1 = {0,0,0,0}, pc0 = {0,0,0,0}, pc1 = {0,0,0,0};
  float cq = 0.f, cc = 0.f;
  float rm[4] = {-1e9f, -1e9f, -1e9f, -1e9f};
  short8 A[12] = {};

  prefetch_stage(qbase, wave, lane, va0, vb0);

  // ---------------- q stages (explicit 2-body unroll keeps banks static) ----
#pragma unroll
  for (int t2 = 0; t2 < NQS; t2 += 2) {
    {  // t = t2 : consume bank0, prefetch bank1
      const int t = t2;
      const char* nb = (t + 1 < NQS) ? qbase + (size_t)(t + 1) * STAGE_BYTES : cbase;
      prefetch_stage(nb, wave, lane, va1, vb1);
      stage_compute<true>(t, va0, vb0, wave, lane, s_qm, s_cm, s_cb, s_qinv, s_cinv, pq0, pq1, cq);
      bar_lgkm();
      if ((wave >> 1) == t) {
        const int lbase = (wave & 1) * 16 + rA;
#pragma unroll
        for (int kk = 0; kk < 12; ++kk) A[kk] = *(const short8*)&s_cb[lbase][kk * 32 + hi * 8];
        asm volatile("s_waitcnt lgkmcnt(0)" ::: "memory");
        __builtin_amdgcn_sched_barrier(0);
      }
      __builtin_amdgcn_s_barrier();
    }
    {  // t = t2+1 : consume bank1, prefetch bank0
      const int t = t2 + 1;
      const char* nb = (t + 1 < NQS) ? qbase + (size_t)(t + 1) * STAGE_BYTES
                                     : cbase + (size_t)(t + 1 - NQS) * STAGE_BYTES;
      prefetch_stage(nb, wave, lane, va0, vb0);
      stage_compute<true>(t, va1, vb1, wave, lane, s_qm, s_cm, s_cb, s_qinv, s_cinv, pq0, pq1, cq);
      bar_lgkm();
      if ((wave >> 1) == t) {
        const int lbase = (wave & 1) * 16 + rA;
#pragma unroll
        for (int kk = 0; kk < 12; ++kk) A[kk] = *(const short8*)&s_cb[lbase][kk * 32 + hi * 8];
        asm volatile("s_waitcnt lgkmcnt(0)" ::: "memory");
        __builtin_amdgcn_sched_barrier(0);
      }
      __builtin_amdgcn_s_barrier();
    }
  }

  // ---------------- c stages ----------------
  for (int tc2 = 0; tc2 < NCS; tc2 += 2) {
#pragma unroll
    for (int sub = 0; sub < 2; ++sub) {
      const int tc = tc2 + sub;
      const char* nb = (tc + 1 < NCS) ? cbase + (size_t)(tc + 1) * STAGE_BYTES : nullptr;
      if (sub == 0) {
        prefetch_stage(nb, wave, lane, va1, vb1);
        stage_compute<false>(tc, va0, vb0, wave, lane, s_qm, s_cm, s_cb, s_qinv, s_cinv, pc0, pc1, cc);
      } else {
        prefetch_stage(nb, wave, lane, va0, vb0);
        stage_compute<false>(tc, va1, vb1, wave, lane, s_qm, s_cm, s_cb, s_qinv, s_cinv, pc0, pc1, cc);
      }
      bar_lgkm();
      f4 acc0 = {0,0,0,0}, acc1 = {0,0,0,0};
#pragma unroll
      for (int kk = 0; kk < 12; ++kk) {
        const short8 b0 = *(const short8*)&s_cb[rA][kk * 32 + hi * 8];
        const short8 b1 = *(const short8*)&s_cb[rA + 16][kk * 32 + hi * 8];
        acc0 = __builtin_amdgcn_mfma_f32_16x16x32_bf16(A[kk], b0, acc0, 0, 0, 0);
        acc1 = __builtin_amdgcn_mfma_f32_16x16x32_bf16(A[kk], b1, acc1, 0, 0, 0);
      }
      const int tb = tc * TR;
      const bool v0 = s_cm[tb + rA] != 0;
      const bool v1 = s_cm[tb + rA + 16] != 0;
      const float ci0 = s_cinv[rA], ci1 = s_cinv[rA + 16];
#pragma unroll
      for (int r = 0; r < 4; ++r) {
        const float qi = s_qinv[wave * 16 + hi * 4 + r];
        const float a0 = v0 ? acc0[r] * (qi * ci0) : -1e9f;
        const float a1 = v1 ? acc1[r] * (qi * ci1) : -1e9f;
        rm[r] = fmaxf(rm[r], fmaxf(a0, a1));
      }
      __builtin_amdgcn_s_barrier();
    }
  }

  // ---------------- epilogue: reductions (reuse s_cb as [16][384] f32) ------
  float* red = (float*)&s_cb[0][0];
  *(f4*)&red[wave * DIM + 4 * lane] = pq0;
  if (lane < 32) *(f4*)&red[wave * DIM + 256 + 4 * lane] = pq1;
  *(f4*)&red[(8 + wave) * DIM + 4 * lane] = pc0;
  if (lane < 32) *(f4*)&red[(8 + wave) * DIM + 256 + 4 * lane] = pc1;
  if (lane == 0) { s_cnt[wave] = cq; s_cnt[8 + wave] = cc; }

#pragma unroll
  for (int r = 0; r < 4; ++r) {
#pragma unroll
    for (int o = 1; o < 16; o <<= 1) rm[r] = fmaxf(rm[r], __shfl_xor(rm[r], o));
  }
  float ps = 0.f;
  if (rA == 0) {
    const int rowb = wave * 16 + hi * 4;
#pragma unroll
    for (int r = 0; r < 4; ++r) ps += s_qm[rowb + r] ? rm[r] : 0.f;
  }
#pragma unroll
  for (int o = 32; o; o >>= 1) ps += __shfl_xor(ps, o);
  if (lane == 0) s_wsum[wave] = ps;
  __syncthreads();

  if (tid < DIM) {
    float sq = 0.f, sc = 0.f, nq = 0.f, nc = 0.f;
#pragma unroll
    for (int w = 0; w < 8; ++w) {
      sq += red[w * DIM + tid];
      sc += red[(8 + w) * DIM + tid];
      nq += s_cnt[w];
      nc += s_cnt[8 + w];
    }
    pooled[b * DIM + tid] = sq / fmaxf(nq, 1e-9f);
    pooled[(NB + b) * DIM + tid] = sc / fmaxf(nc, 1e-9f);
  }
  if (tid == 0) {
    float tot = 0.f;
#pragma unroll
    for (int w = 0; w < 8; ++w) tot += s_wsum[w];
    late[b] = tot;
  }
}

// Round-1 proven shape: 1 pooled row per block, grid (256, 2).
__global__ __launch_bounds__(DIM)
void mlp_kernel(const float* __restrict__ pooled,
                const float* __restrict__ W1, const float* __restrict__ b1,
                const float* __restrict__ W2, const float* __restrict__ b2,
                float* __restrict__ emb) {
  __shared__ float s_in[DIM];
  __shared__ float s_h[DIM];
  __shared__ float s_red[6];
  const int row = blockIdx.y * NB + blockIdx.x;
  const int d = threadIdx.x;
  s_in[d] = pooled[(size_t)row * DIM + d];
  __syncthreads();
  float acc = b1[d];
#pragma unroll 8
  for (int k = 0; k < DIM; ++k) acc = fmaf(s_in[k], W1[k * DIM + d], acc);
  s_h[d] = fmaxf(acc, 0.f);
  __syncthreads();
  float p = b2[d];
#pragma unroll 8
  for (int k = 0; k < DIM; ++k) p = fmaf(s_h[k], W2[k * DIM + d], p);
  float ss = p * p;
#pragma unroll
  for (int o = 32; o; o >>= 1) ss += __shfl_xor(ss, o);
  if ((d & 63) == 0) s_red[d >> 6] = ss;
  __syncthreads();
  float tot = 0.f;
#pragma unroll
  for (int w = 0; w < 6; ++w) tot += s_red[w];
  emb[(size_t)row * DIM + d] = p * (1.0f / fmaxf(sqrtf(tot), 1e-12f));
}

// Round-1 proven shape: out0[i][j] = dot(q_emb[i], c_emb[j]) / 0.07
__global__ __launch_bounds__(NB)
void contrast_kernel(const float* __restrict__ emb, float* __restrict__ out0) {
  __shared__ float s_q[DIM];
  const int i = blockIdx.x;
  for (int k = threadIdx.x; k < DIM; k += NB) s_q[k] = emb[(size_t)i * DIM + k];
  __syncthreads();
  const float* ce = emb + (size_t)(NB + threadIdx.x) * DIM;
  float acc = 0.f;
#pragma unroll 8
  for (int k = 0; k < DIM; ++k) acc = fmaf(s_q[k], ce[k], acc);
  out0[(size_t)i * NB + threadIdx.x] = acc / 0.07f;
}

extern "C" void kernel_launch(void* const* d_in, const int* in_sizes, int n_in,
                              void* d_out, int out_size, void* d_ws, size_t ws_size,
                              hipStream_t stream) {
  const float* qtok = (const float*)d_in[0];
  const float* ctok = (const float*)d_in[1];
  const int*   qmm  = (const int*)d_in[2];
  const int*   cmm  = (const int*)d_in[3];
  const float* W1   = (const float*)d_in[4];
  const float* b1   = (const float*)d_in[5];
  const float* W2   = (const float*)d_in[6];
  const float* b2   = (const float*)d_in[7];

  float* out0 = (float*)d_out;            // [NB*NB]
  float* late = out0 + NB * NB;           // [NB]
  float* pooled = (float*)d_ws;           // [2*NB][DIM]
  float* emb    = pooled + 2 * NB * DIM;  // [2*NB][DIM]

  hipLaunchKernelGGL(fused_pool_late, dim3(NB), dim3(512), 0, stream,
                     qtok, ctok, qmm, cmm, pooled, late);
  hipLaunchKernelGGL(mlp_kernel, dim3(NB, 2), dim3(DIM), 0, stream,
                     pooled, W1, b1, W2, b2, emb);
  hipLaunchKernelGGL(contrast_kernel, dim3(NB), dim3(NB), 0, stream, emb, out0);
}